// Round 8
// baseline (103.518 us; speedup 1.0000x reference)
//
#include <hip/hip_runtime.h>
#include <hip/hip_bf16.h>

#define B_ 4
#define C_IN_ 384
#define C_OUT_ 768
#define N_ 8192
#define K_ 16
#define FANIN_ 192     // 2*C_IN/GROUPS
#define NT 32          // n-columns per block
#define PADC (2*C_IN_ + 8)   // 776 shorts: pad to break 1552B-stride bank conflicts

typedef float f32x4 __attribute__((ext_vector_type(4)));
typedef short bf16x8 __attribute__((ext_vector_type(8)));

__device__ __forceinline__ unsigned short f2b(float f) {
  union { float f; unsigned u; } v; v.f = f;
  unsigned r = v.u + 0x7FFFu + ((v.u >> 16) & 1u);  // RNE
  return (unsigned short)(r >> 16);
}

// ---- kernel 1: W fp32 -> bf16 (original fanin order: interleaved (x,rel)) ----
__global__ __launch_bounds__(256) void wconv_kernel(const float* __restrict__ W,
                                                    unsigned short* __restrict__ Wb) {
  int i = blockIdx.x * 256 + threadIdx.x;
  if (i < C_OUT_ * FANIN_) Wb[i] = f2b(W[i]);
}

// ---- kernel 2: transpose x [B][C][N] f32 -> xt [B][N][C] bf16 + xq int8 (x16) ----
__global__ __launch_bounds__(256) void transpose_kernel(const float* __restrict__ x,
                                                        unsigned short* __restrict__ xt,
                                                        char* __restrict__ xq) {
  __shared__ float tile[32][65];
  int n0 = blockIdx.x * 32;
  int c0 = blockIdx.y * 64;
  int b  = blockIdx.z;
  int tx = threadIdx.x & 31;
  int ty = threadIdx.x >> 5;
  const float* xp = x + (size_t)b * C_IN_ * N_;
  #pragma unroll
  for (int r = 0; r < 8; ++r) {
    int c = c0 + r * 8 + ty;
    tile[tx][r * 8 + ty] = xp[(size_t)c * N_ + n0 + tx];   // coalesced along n
  }
  __syncthreads();
  // bf16 out (exact self values)
  unsigned short* outp = xt + ((size_t)b * N_ + n0) * C_IN_ + c0;
  int cp = threadIdx.x & 31;
  int ny = threadIdx.x >> 5;
  #pragma unroll
  for (int p = 0; p < 4; ++p) {
    int nl = ny + p * 8;
    unsigned pk = (unsigned)f2b(tile[nl][cp * 2]) |
                  ((unsigned)f2b(tile[nl][cp * 2 + 1]) << 16);
    *(unsigned*)(outp + (size_t)nl * C_IN_ + cp * 2) = pk;
  }
  // int8 out (scale 16, RN, clamp +-127), linear channel order
  char* qout = xq + ((size_t)b * N_ + n0) * C_IN_ + c0;
  #pragma unroll
  for (int u = 0; u < 2; ++u) {
    int uu = u * 256 + threadIdx.x;
    int nl = uu >> 4;            // 0..31
    int c4 = uu & 15;            // dword within the 64-channel slab
    unsigned pk = 0;
    #pragma unroll
    for (int e = 0; e < 4; ++e) {
      int q = __float2int_rn(tile[nl][c4 * 4 + e] * 16.0f);
      q = q > 127 ? 127 : (q < -127 ? -127 : q);
      pk |= ((unsigned)(q & 0xff)) << (8 * e);
    }
    *(unsigned*)(qout + (size_t)nl * C_IN_ + c4 * 4) = pk;
  }
}

// ---- kernel 3: int8 gather+max (32 loads in flight) -> LDS tile -> MFMA ----
__global__ __launch_bounds__(512) void mrconv_kernel(
    const unsigned short* __restrict__ xt,   // [B][N][384] bf16 (self, exact)
    const char* __restrict__ xq,             // [B][N][384] int8 (gather, x16)
    const int* __restrict__ eidx,            // [2][B][N][K]
    const unsigned short* __restrict__ Wb,   // [C_OUT][FANIN] bf16
    const float* __restrict__ bias,          // [C_OUT]
    float* __restrict__ out)                 // [B][C_OUT][N]
{
  __shared__ unsigned short m_lds[NT][PADC];  // merged: interleaved (x_c, rel_c)
  int tile = blockIdx.x;
  int b    = blockIdx.y;
  int n0   = tile * NT;
  int tid  = threadIdx.x;
  int wv   = tid >> 6;
  int lane = tid & 63;

  const unsigned short* xtb = xt + (size_t)b * N_ * C_IN_;
  const char* xqb = xq + (size_t)b * N_ * C_IN_;
  const int* e0p = eidx + ((size_t)b * N_) * K_;          // edge_index[0][b] -> j
  const int* e1p = eidx + ((size_t)(B_ + b) * N_) * K_;   // edge_index[1][b] -> i

  // -------- phase 1: gather + max-relative (48 lanes x 8 ch) --------
  for (int s = 0; s < 4; ++s) {
    int nl = wv * 4 + s;                                   // 8 waves x 4 cols = 32
    int nb = __builtin_amdgcn_readfirstlane(n0 + nl);
    const int* e0 = e0p + (size_t)nb * K_;
    const int* e1 = e1p + (size_t)nb * K_;
    if (lane < 48) {
      uint4 xv = *(const uint4*)(xtb + (size_t)nb * C_IN_ + lane * 8);  // self bf16
      const char* xqc = xqb + lane * 8;                    // int8 channel base

      // ---- issue phase: ALL 32 gathers outstanding, no consumption between ----
      uint2 vj[K_], vi[K_];
      #pragma unroll
      for (int k = 0; k < K_; ++k) {
        int j = __builtin_amdgcn_readfirstlane(e0[k]);
        vj[k] = *(const uint2*)(xqc + (size_t)j * C_IN_);  // 8 int8 ch
      }
      #pragma unroll
      for (int k = 0; k < K_; ++k) {
        int i = __builtin_amdgcn_readfirstlane(e1[k]);
        vi[k] = *(const uint2*)(xqc + (size_t)i * C_IN_);
      }

      // ---- consume phase ----
      int mx[8];
      #pragma unroll
      for (int c = 0; c < 8; ++c) mx[c] = -512;
      #pragma unroll
      for (int k = 0; k < K_; ++k) {
        unsigned aj[2] = {vj[k].x, vj[k].y};
        unsigned ai[2] = {vi[k].x, vi[k].y};
        #pragma unroll
        for (int d = 0; d < 2; ++d)
          #pragma unroll
          for (int e = 0; e < 4; ++e) {
            int sj = (int)(signed char)((aj[d] >> (8 * e)) & 0xffu);
            int si = (int)(signed char)((ai[d] >> (8 * e)) & 0xffu);
            int df = sj - si;
            mx[4 * d + e] = df > mx[4 * d + e] ? df : mx[4 * d + e];
          }
      }

      // pack interleaved (x_c, rel_c): dword c = x_c | rel_c<<16
      unsigned ux[4] = {xv.x, xv.y, xv.z, xv.w};
      unsigned od[8];
      #pragma unroll
      for (int c = 0; c < 8; ++c) {
        unsigned xs = (ux[c >> 1] >> ((c & 1) * 16)) & 0xffffu;
        od[c] = xs | ((unsigned)f2b((float)mx[c] * 0.0625f) << 16);
      }
      uint4 o0; o0.x = od[0]; o0.y = od[1]; o0.z = od[2]; o0.w = od[3];
      uint4 o1; o1.x = od[4]; o1.y = od[5]; o1.z = od[6]; o1.w = od[7];
      *(uint4*)&m_lds[nl][lane * 16] = o0;
      *(uint4*)&m_lds[nl][lane * 16 + 8] = o1;
    }
  }
  __syncthreads();

  // -------- phase 2: grouped GEMM via MFMA (R2-verified) --------
  // wave wv -> group g = wv>>1, cout half = wv&1: owns 96 rows x 32 cols
  int g    = wv >> 1;
  int half = wv & 1;
  int rb   = g * 192 + half * 96;    // cout base
  int l15  = lane & 15;
  int lhi  = lane >> 4;

  f32x4 acc[6][2];
  #pragma unroll
  for (int rt = 0; rt < 6; ++rt)
    #pragma unroll
    for (int ct = 0; ct < 2; ++ct)
      acc[rt][ct] = (f32x4){0.f, 0.f, 0.f, 0.f};

  #pragma unroll
  for (int ks = 0; ks < 6; ++ks) {           // K = 192 = 6 x 32
    int k0 = ks * 32 + lhi * 8;
    bf16x8 bfrag[2];
    #pragma unroll
    for (int ct = 0; ct < 2; ++ct) {
      int n = ct * 16 + l15;
      bfrag[ct] = *(const bf16x8*)&m_lds[n][g * FANIN_ + k0];   // B[k][n]
    }
    #pragma unroll
    for (int rt = 0; rt < 6; ++rt) {
      int co = rb + rt * 16 + l15;
      bf16x8 afrag = *(const bf16x8*)(Wb + (size_t)co * FANIN_ + k0);  // A[m][k]
      #pragma unroll
      for (int ct = 0; ct < 2; ++ct)
        acc[rt][ct] = __builtin_amdgcn_mfma_f32_16x16x32_bf16(afrag, bfrag[ct],
                                                              acc[rt][ct], 0, 0, 0);
    }
  }

  // -------- epilogue: bias + ReLU, store --------
  float* outb = out + (size_t)b * C_OUT_ * N_;
  #pragma unroll
  for (int rt = 0; rt < 6; ++rt) {
    int co_b = rb + rt * 16 + lhi * 4;       // D row = (lane>>4)*4 + reg (m89-verified)
    #pragma unroll
    for (int ct = 0; ct < 2; ++ct) {
      int n = n0 + ct * 16 + l15;            // D col = lane&15
      #pragma unroll
      for (int r = 0; r < 4; ++r) {
        int co = co_b + r;
        float v = acc[rt][ct][r] + bias[co];
        outb[(size_t)co * N_ + n] = v > 0.f ? v : 0.f;
      }
    }
  }
}

extern "C" void kernel_launch(void* const* d_in, const int* in_sizes, int n_in,
                              void* d_out, int out_size, void* d_ws, size_t ws_size,
                              hipStream_t stream) {
  const float* x    = (const float*)d_in[0];
  const int*   eidx = (const int*)d_in[1];
  const float* W    = (const float*)d_in[2];
  const float* bias = (const float*)d_in[3];
  float* out = (float*)d_out;

  unsigned short* xt = (unsigned short*)d_ws;                 // 25.2 MB bf16
  unsigned short* Wb = xt + (size_t)B_ * N_ * C_IN_;          // 0.3 MB bf16
  char*           xq = (char*)(Wb + (size_t)C_OUT_ * FANIN_); // 12.6 MB int8

  wconv_kernel<<<(C_OUT_ * FANIN_ + 255) / 256, 256, 0, stream>>>(W, Wb);

  dim3 tg(N_ / 32, C_IN_ / 64, B_);
  transpose_kernel<<<tg, 256, 0, stream>>>(x, xt, xq);

  dim3 mg(N_ / NT, B_);
  mrconv_kernel<<<mg, 512, 0, stream>>>(xt, xq, eidx, Wb, bias, out);
}